// Round 23
// baseline (141.861 us; speedup 1.0000x reference)
//
#include <hip/hip_runtime.h>

// Roformer MHA: T=2048 B=2 E=1024 H=16 HD=64
#define T_  2048
#define B_  2
#define E_  1024
#define H_  16
#define HD_ 64
#define M_  4096          // T*B rows
#define N_QKV 3072        // 3*E

typedef unsigned short u16;
typedef unsigned int   u32;
typedef __attribute__((ext_vector_type(8))) __bf16 bf16x8;
typedef __attribute__((ext_vector_type(4))) float  f32x4;

__device__ inline u16 f2bf(float f) {
  u32 u = __float_as_uint(f);
  u += 0x7fffu + ((u >> 16) & 1u);   // RTNE (finite values)
  return (u16)(u >> 16);
}

__device__ inline u32 cvtpk(float lo, float hi) {   // dst.lo=bf16(lo), dst.hi=bf16(hi)
  u32 r;
  asm("v_cvt_pk_bf16_f32 %0, %1, %2" : "=v"(r) : "v"(lo), "v"(hi));
  return r;
}

// fast 2^x: raw v_exp_f32 (no OCML edge-case bloat)
__device__ inline float ex2(float x) {
#if __has_builtin(__builtin_amdgcn_exp2f)
  return __builtin_amdgcn_exp2f(x);
#else
  return __expf(x * 0.69314718f);
#endif
}

__device__ inline void gl_lds16(const u16* g, u16* l) {
  __builtin_amdgcn_global_load_lds(
      (const __attribute__((address_space(1))) u32*)g,
      (__attribute__((address_space(3))) u32*)l, 16, 0, 0);
}

// T1: bijective XCD-aware block swizzle (requires nwg % 8 == 0)
__device__ inline int xcd_swz(int orig, int nwg) {
  return (orig & 7) * (nwg >> 3) + (orig >> 3);
}

// ---------------- Pass A: fp32 -> bf16 conversion (weights only) -----------
__global__ __launch_bounds__(256) void cvt_kernel(
    const float* __restrict__ wi, const float* __restrict__ wo,
    u16* __restrict__ Wi, u16* __restrict__ Wo) {
  int idx = blockIdx.x * 256 + threadIdx.x;       // one float4 per thread
  const int n1 = (3 * E_ * E_) / 4;
  const float4* src; u16* dst; int i;
  if (idx < n1) { src = (const float4*)wi; dst = Wi; i = idx; }
  else          { src = (const float4*)wo; dst = Wo; i = idx - n1; }
  float4 v = src[i];
  uint2 o;
  o.x = (u32)f2bf(v.x) | ((u32)f2bf(v.y) << 16);
  o.y = (u32)f2bf(v.z) | ((u32)f2bf(v.w) << 16);
  *(uint2*)&dst[(size_t)i * 4] = o;
}

// ---------------- Pass B: QKV GEMM + bias + scale + RoPE -------------------
// 128x128 tile, 512 threads (8 waves as 2M x 4N, each 64x32 out).
// A-operand (X) staged DIRECTLY AS FP32 via gl_lds (no bf16 round-trip
// through HBM); converted to bf16 fragments at LDS-read time via cvt_pk.
// A chunks XOR-swizzled by row&7 (2-way banks = free); B path as R21.
// 2-phase dbuf. Epilogue: staged-transpose through dead LDS.
// q is pre-scaled by HD^-0.5 * log2(e) so attention softmax can use exp2.
__global__ __launch_bounds__(512) void gemm_qkv(
    const float* __restrict__ X, const u16* __restrict__ W,
    const float* __restrict__ bias, const float* __restrict__ rel,
    u16* __restrict__ qb, u16* __restrict__ kp, u16* __restrict__ vp) {
  const int K = E_;
  __shared__ u16 SH[24576];                         // 48KB: A 2x16K(fp32) + B 2x8K
  float* Afp = (float*)SH;                          // [2][4096] floats
  u16 (*Bs)[4096] = (u16(*)[4096])(SH + 16384);
  int orig = blockIdx.y * gridDim.x + blockIdx.x;
  int wgid = xcd_swz(orig, 32 * 24);
  const int tm = (wgid & 31) * 128, tn = (wgid >> 5) * 128;
  const int tid = threadIdx.x;
  const int w = tid >> 6, lane = tid & 63, lr = lane & 15, lg = lane >> 4;
  const int wm = (w >> 2) * 64, wn = (w & 3) * 32;
  auto stage = [&](int buf, int k0) {
    #pragma unroll
    for (int h = 0; h < 2; ++h) {                   // A: 1024 fp32 16B-chunks
      int ca = tid + h * 512;
      int row = ca >> 3;
      int lc = (ca & 7) ^ (row & 7);                // inverse-swizzled source
      gl_lds16((const u16*)(X + (size_t)(tm + row) * K + k0 + lc * 4),
               (u16*)(Afp + buf * 4096 + ca * 4));
    }
    int cb = tid;                                   // B: 512 bf16 granules
    int gb = cb ^ ((cb >> 3) & 3);
    gl_lds16(W + (size_t)(tn + (gb >> 2)) * K + k0 + (gb & 3) * 8,
             &Bs[buf][cb * 8]);
  };
  f32x4 acc[4][2] = {};
  stage(0, 0);
  __syncthreads();
  for (int it = 0; it < 32; ++it) {
    int cur = it & 1;
    if (it < 31) stage(cur ^ 1, (it + 1) * 32);
    bf16x8 af[4], bq[2];
    #pragma unroll
    for (int mi = 0; mi < 4; ++mi) {
      int row = wm + mi * 16 + lr;
      int s = row & 7;
      const float* rp = Afp + cur * 4096 + row * 32;
      f32x4 lo = *(const f32x4*)(rp + ((lg * 2) ^ s) * 4);
      f32x4 hi = *(const f32x4*)(rp + ((lg * 2 + 1) ^ s) * 4);
      u32 fr[4] = {cvtpk(lo[0], lo[1]), cvtpk(lo[2], lo[3]),
                   cvtpk(hi[0], hi[1]), cvtpk(hi[2], hi[3])};
      af[mi] = *(const bf16x8*)fr;
    }
    #pragma unroll
    for (int ni = 0; ni < 2; ++ni) {
      int ga = (wn + ni * 16 + lr) * 4 + lg; ga ^= (ga >> 3) & 3;
      bq[ni] = *(const bf16x8*)&Bs[cur][ga * 8];
    }
    #pragma unroll
    for (int mi = 0; mi < 4; ++mi)
      #pragma unroll
      for (int ni = 0; ni < 2; ++ni)
        acc[mi][ni] = __builtin_amdgcn_mfma_f32_16x16x32_bf16(
            af[mi], bq[ni], acc[mi][ni], 0, 0, 0);
    __syncthreads();                    // drains stage loads; cur reads done
  }
  // ---- epilogue: build LDS image (4 chunks x 4096 u16), then dump ----
  const int sect = tn >> 10;                        // uniform per block
  #pragma unroll
  for (int ni = 0; ni < 2; ++ni) {
    int n = tn + wn + ni * 16 + lr;
    float bv = bias[n];
    int nn = n & 1023;
    int d = nn & 63, i2 = d >> 1;
    int hsub = (nn >> 6) & 1;
    #pragma unroll
    for (int mi = 0; mi < 4; ++mi) {
      #pragma unroll
      for (int r = 0; r < 4; ++r) {
        int m = tm + wm + mi * 16 + lg * 4 + r;
        int t = m >> 1, bb = m & 1, tl = t & 63;
        float v = acc[mi][ni][r] + bv;
        if (sect == 0) v *= 0.18033688f;            // HD^-0.5 * log2(e)
        if (sect < 2) {                             // RoPE (uniform branch)
          float partner = __shfl_xor(v, 1);
          float sp = rel[t * HD_ + i2];
          float cp = rel[t * HD_ + 32 + i2];
          float rot = (d & 1) ? partner : -partner;
          v = v * cp + rot * sp;
        }
        int off;
        if (sect == 0)
          off = tl * 64 + d;                        // q: row-major [t][d]
        else if (sect == 1)
          off = (((tl >> 4) * 2 + (d >> 5)) << 9)   // K frag-major
              + (((d >> 3) & 3) << 7) + ((tl & 15) << 3) + (d & 7);
        else
          off = (((tl >> 5) * 4 + (d >> 4)) << 9)   // V^T frag-major
              + (((tl >> 3) & 3) << 7) + ((d & 15) << 3) + (tl & 7);
        SH[((bb << 1) | hsub) * 4096 + off] = f2bf(v);
      }
    }
  }
  __syncthreads();
  {
    // chunk c = w>>1 (= (bb<<1)|hsub); each chunk dumped by 2 waves
    int h0 = (tn & 1023) >> 6;
    int c = w >> 1, half = w & 1;
    int bb = c >> 1, hs = c & 1;
    int bh = bb * H_ + h0 + hs;
    int t0 = tm >> 1;
    u16* dst;
    if (sect == 0)      dst = qb + ((size_t)bh * T_ + t0) * HD_;
    else if (sect == 1) dst = kp + (((size_t)bh * 32 + (t0 >> 6)) << 12);
    else                dst = vp + (((size_t)bh * 32 + (t0 >> 6)) << 12);
    const u16* srcp = SH + c * 4096;
    #pragma unroll
    for (int i = 0; i < 4; ++i) {
      int g = half * 256 + i * 64 + lane;
      *(uint4*)&dst[(size_t)g * 8] = *(const uint4*)&srcp[g * 8];
    }
  }
}

// ---------------- Pass D: flash attention ----------------------------------
// R21 config: 512 thr / 8 waves, 128 q rows, grid (T/128, BH) = 512 = 2/CU,
// KVBLK=128 (16 iters), LDS 64KB. Softmax log2-domain raw v_exp, tree
// reductions, lane-local defer-max, lane-partial l; P->PV in-register via
// cvt_pk + permlane swaps; T5 setprio around MFMA clusters.
__global__ __launch_bounds__(512) void attn_kernel(
    const u16* __restrict__ qbm, const u16* __restrict__ kp,
    const u16* __restrict__ vp, u16* __restrict__ attnb) {
  __shared__ u16 Kl[2][8192];                 // 2 x 16KB
  __shared__ u16 Vl[2][8192];                 // 2 x 16KB
  int orig = blockIdx.y * gridDim.x + blockIdx.x;
  int wgid = xcd_swz(orig, 16 * 32);
  int bh = wgid >> 4;
  int tid = threadIdx.x;
  int w = tid >> 6, lane = tid & 63, lr = lane & 15, lg = lane >> 4;
  int qbase = (wgid & 15) * 128 + w * 16;
  const u16* qrow  = qbm + (size_t)bh * T_ * HD_;
  const u16* ktile = kp + ((size_t)bh * 32) * 4096;
  const u16* vtile = vp + ((size_t)bh * 32) * 4096;
  bf16x8 qf[2];
  #pragma unroll
  for (int ks = 0; ks < 2; ++ks)
    qf[ks] = *(const bf16x8*)&qrow[(size_t)(qbase + lr) * HD_ + ks * 32 + lg * 8];
  auto stage = [&](int buf, int kt) {         // kt in 128-kv units
    const u16* kn = ktile + ((size_t)kt) * 8192;
    const u16* vn = vtile + ((size_t)kt) * 8192;
    gl_lds16(kn + (size_t)tid * 8,         &Kl[buf][(w * 64) * 8]);
    gl_lds16(kn + (size_t)(tid + 512) * 8, &Kl[buf][(w * 64 + 512) * 8]);
    gl_lds16(vn + (size_t)tid * 8,         &Vl[buf][(w * 64) * 8]);
    gl_lds16(vn + (size_t)(tid + 512) * 8, &Vl[buf][(w * 64 + 512) * 8]);
  };
  f32x4 o[4] = {};
  float mrun = -INFINITY, lrun = 0.f;        // lrun is LANE-PARTIAL
  stage(0, 0);
  __syncthreads();
  for (int kt = 0; kt < 16; ++kt) {
    int cur = kt & 1;
    if (kt < 15) stage(cur ^ 1, kt + 1);
    // QK^T (swapped): st[kb4][r] = S[kv = kb4*16+lg*4+r][q = lr], kb4 0..7
    f32x4 st[8];
    __builtin_amdgcn_s_setprio(1);
    #pragma unroll
    for (int kb4 = 0; kb4 < 8; ++kb4) {
      st[kb4] = (f32x4){0.f, 0.f, 0.f, 0.f};
      #pragma unroll
      for (int ks = 0; ks < 2; ++ks) {
        bf16x8 a = *(const bf16x8*)&Kl[cur][(kb4 * 2 + ks) * 512 + lane * 8];
        st[kb4] = __builtin_amdgcn_mfma_f32_16x16x32_bf16(a, qf[ks], st[kb4], 0, 0, 0);
      }
    }
    __builtin_amdgcn_s_setprio(0);
    // lane-local tree max; cross-lane shfls only when rescale triggers
    float mm[8];
    #pragma unroll
    for (int kb4 = 0; kb4 < 8; ++kb4)
      mm[kb4] = fmaxf(fmaxf(st[kb4][0], st[kb4][1]),
                      fmaxf(st[kb4][2], st[kb4][3]));
    float mxl = fmaxf(fmaxf(fmaxf(mm[0], mm[1]), fmaxf(mm[2], mm[3])),
                      fmaxf(fmaxf(mm[4], mm[5]), fmaxf(mm[6], mm[7])));
    if (!__all(mxl <= mrun + 11.5f)) {       // T13 defer-max (log2 domain)
      float mx = fmaxf(mxl, __shfl_xor(mxl, 16));
      mx = fmaxf(mx, __shfl_xor(mx, 32));
      float mnew = fmaxf(mrun, mx);
      float sc = ex2(mrun - mnew);
      lrun *= sc;                            // partial scales uniformly
      #pragma unroll
      for (int db = 0; db < 4; ++db) o[db] *= sc;
      mrun = mnew;
    }
    u32 cv[8][2];
    float s01 = 0.f, s23 = 0.f;
    #pragma unroll
    for (int kb4 = 0; kb4 < 8; ++kb4) {
      float p0 = ex2(st[kb4][0] - mrun);
      float p1 = ex2(st[kb4][1] - mrun);
      float p2 = ex2(st[kb4][2] - mrun);
      float p3 = ex2(st[kb4][3] - mrun);
      if (kb4 & 2) s23 += (p0 + p1) + (p2 + p3);
      else         s01 += (p0 + p1) + (p2 + p3);
      cv[kb4][0] = cvtpk(p0, p1);            // lo=r0, hi=r1
      cv[kb4][1] = cvtpk(p2, p3);
    }
    lrun += s01 + s23;                       // lane-partial; no shfl here
    // PV over 128 kv = 4 k-slots of 32; in-register P redistribution.
    #pragma unroll
    for (int ks = 0; ks < 4; ++ks) {
      u32 a = cv[ks * 2][0], b = cv[ks * 2][1];
      u32 c = cv[ks * 2 + 1][0], d = cv[ks * 2 + 1][1];
      asm("v_permlane32_swap_b32 %0, %1" : "+v"(a), "+v"(c));
      asm("v_permlane32_swap_b32 %0, %1" : "+v"(b), "+v"(d));
      asm("v_permlane16_swap_b32 %0, %1" : "+v"(a), "+v"(c));
      asm("v_permlane16_swap_b32 %0, %1" : "+v"(b), "+v"(d));
      u32 pf32[4] = {a, b, c, d};
      bf16x8 pf = *(const bf16x8*)pf32;
      __builtin_amdgcn_s_setprio(1);
      #pragma unroll
      for (int db = 0; db < 4; ++db) {
        bf16x8 vf = *(const bf16x8*)&Vl[cur][(ks * 4 + db) * 512 + lane * 8];
        o[db] = __builtin_amdgcn_mfma_f32_16x16x32_bf16(vf, pf, o[db], 0, 0, 0);
      }
      __builtin_amdgcn_s_setprio(0);
    }
    __syncthreads();                         // drains vmcnt: next tile ready
  }
  // final cross-lane l reduce (deferred from the loop)
  lrun += __shfl_xor(lrun, 16);
  lrun += __shfl_xor(lrun, 32);
  float inv = 1.f / lrun;
  int bb = bh >> 4, h = bh & 15;
  int m = (qbase + lr) * 2 + bb;
  #pragma unroll
  for (int db = 0; db < 4; ++db) {
    uint2 u;
    u.x = cvtpk(o[db][0] * inv, o[db][1] * inv);
    u.y = cvtpk(o[db][2] * inv, o[db][3] * inv);
    *(uint2*)&attnb[(size_t)m * E_ + h * 64 + db * 16 + lg * 4] = u;
  }
}

// ---------------- Pass E: out projection GEMM ------------------------------
// out[m][n] = sum_e A[m][e] * W[n][e] + bias[n],  fp32 out
// 64x64 tile (grid 1024 = 4 blocks/CU; LDS 16KB). 4 waves as 2M x 2N,
// each 32x32 out; 2-phase dbuf + granule swizzle.
__global__ __launch_bounds__(256) void gemm_out(
    const u16* __restrict__ A, const u16* __restrict__ W,
    const float* __restrict__ bias, float* __restrict__ out) {
  const int K = E_;
  __shared__ u16 As[2][2048];
  __shared__ u16 Bs[2][2048];
  int orig = blockIdx.y * gridDim.x + blockIdx.x;
  int wgid = xcd_swz(orig, 64 * 16);
  const int tm = (wgid & 63) * 64, tn = (wgid >> 6) * 64;
  const int tid = threadIdx.x;
  const int w = tid >> 6, lane = tid & 63, lr = lane & 15, lg = lane >> 4;
  const int wm = (w >> 1) * 32, wn = (w & 1) * 32;
  auto stage = [&](int buf, int k0) {
    int ca = w * 64 + lane;                         // granules 0..255
    int ga = ca ^ ((ca >> 3) & 3);
    gl_lds16(A + (size_t)(tm + (ga >> 2)) * K + k0 + (ga & 3) * 8,
             &As[buf][ca * 8]);
    gl_lds16(W + (size_t)(tn + (ga >> 2)) * K + k0 + (ga & 3) * 8,
             &Bs[buf][ca * 8]);
  };
  f32x4 acc[2][2] = {};
  stage(0, 0);
  __syncthreads();
  for (int it = 0; it < 32; ++it) {
    int cur = it & 1;
    if (it < 31) stage(cur ^ 1, (it + 1) * 32);
    bf16x8 af[2], bq[2];
    #pragma unroll
    for (int mi = 0; mi < 2; ++mi) {
      int ga = (wm + mi * 16 + lr) * 4 + lg; ga ^= (ga >> 3) & 3;
      af[mi] = *(const bf16x8*)&As[cur][ga * 8];
    }
    #pragma unroll
    for (int ni = 0; ni < 2; ++ni) {
      int gb = (wn + ni * 16 + lr) * 4 + lg; gb ^= (gb >> 3) & 3;
      bq[ni] = *(const bf16x8*)&Bs[cur][gb * 8];
    }
    #pragma unroll
    for (int mi = 0; mi < 2; ++mi)
      #pragma unroll
      for (int ni = 0; ni < 2; ++ni)
        acc[mi][ni] = __builtin_amdgcn_mfma_f32_16x16x32_bf16(
            af[mi], bq[ni], acc[mi][ni], 0, 0, 0);
    __syncthreads();
  }
  #pragma unroll
  for (int ni = 0; ni < 2; ++ni) {
    int n = tn + wn + ni * 16 + lr;
    float bv = bias[n];
    #pragma unroll
    for (int mi = 0; mi < 2; ++mi) {
      #pragma unroll
      for (int r = 0; r < 4; ++r) {
        int m = tm + wm + mi * 16 + lg * 4 + r;
        out[(size_t)m * E_ + n] = acc[mi][ni][r] + bv;
      }
    }
  }
}

// ---------------- launch ----------------------------------------------------
extern "C" void kernel_launch(void* const* d_in, const int* in_sizes, int n_in,
                              void* d_out, int out_size, void* d_ws, size_t ws_size,
                              hipStream_t stream) {
  const float* q   = (const float*)d_in[0];
  const float* rel = (const float*)d_in[1];
  const float* wi  = (const float*)d_in[2];
  const float* bi  = (const float*)d_in[3];
  const float* wo  = (const float*)d_in[4];
  const float* bo  = (const float*)d_in[5];
  float* out = (float*)d_out;
  char* ws = (char*)d_ws;
  // ws layout (bytes), 40 MiB total:
  u16* Wib = (u16*)(ws + 8388608);          //  6 MiB  [3072][1024]
  u16* Wob = (u16*)(ws + 14680064);         //  2 MiB  [1024][1024]
  u16* qb  = (u16*)(ws + 16777216);         //  8 MiB  [32][2048][64]
  u16* kpb = (u16*)(ws + 25165824);         //  8 MiB  [32][32][4096] frag-major
  u16* vpb = (u16*)(ws + 33554432);         //  8 MiB  [32][32][4096] frag-major
  u16* attnb = (u16*)ws;                    //  8 MiB  (former X region, unused)

  cvt_kernel<<<dim3(4096), dim3(256), 0, stream>>>(wi, wo, Wib, Wob);
  gemm_qkv<<<dim3(32, 24), dim3(512), 0, stream>>>(q, Wib, bi, rel, qb, kpb, vpb);
  attn_kernel<<<dim3(16, 32), dim3(512), 0, stream>>>(qb, kpb, vpb, attnb);
  gemm_out<<<dim3(64, 16), dim3(256), 0, stream>>>(attnb, Wob, bo, out);
}

// Round 24
// 122.043 us; speedup vs baseline: 1.1624x; 1.1624x over previous
//
#include <hip/hip_runtime.h>

// Roformer MHA: T=2048 B=2 E=1024 H=16 HD=64
#define T_  2048
#define B_  2
#define E_  1024
#define H_  16
#define HD_ 64
#define M_  4096          // T*B rows
#define N_QKV 3072        // 3*E

typedef unsigned short u16;
typedef unsigned int   u32;
typedef __attribute__((ext_vector_type(8))) __bf16 bf16x8;
typedef __attribute__((ext_vector_type(4))) float  f32x4;

__device__ inline u16 f2bf(float f) {
  u32 u = __float_as_uint(f);
  u += 0x7fffu + ((u >> 16) & 1u);   // RTNE (finite values)
  return (u16)(u >> 16);
}

__device__ inline u32 cvtpk(float lo, float hi) {   // dst.lo=bf16(lo), dst.hi=bf16(hi)
  u32 r;
  asm("v_cvt_pk_bf16_f32 %0, %1, %2" : "=v"(r) : "v"(lo), "v"(hi));
  return r;
}

// fast 2^x: raw v_exp_f32 (no OCML edge-case bloat)
__device__ inline float ex2(float x) {
#if __has_builtin(__builtin_amdgcn_exp2f)
  return __builtin_amdgcn_exp2f(x);
#else
  return __expf(x * 0.69314718f);
#endif
}

__device__ inline void gl_lds16(const u16* g, u16* l) {
  __builtin_amdgcn_global_load_lds(
      (const __attribute__((address_space(1))) u32*)g,
      (__attribute__((address_space(3))) u32*)l, 16, 0, 0);
}

// T1: bijective XCD-aware block swizzle (requires nwg % 8 == 0)
__device__ inline int xcd_swz(int orig, int nwg) {
  return (orig & 7) * (nwg >> 3) + (orig >> 3);
}

// ---------------- Pass A: fp32 -> bf16 conversion --------------------------
__global__ __launch_bounds__(256) void cvt_kernel(
    const float* __restrict__ q, const float* __restrict__ wi,
    const float* __restrict__ wo, u16* __restrict__ X,
    u16* __restrict__ Wi, u16* __restrict__ Wo) {
  int idx = blockIdx.x * 256 + threadIdx.x;       // one float4 per thread
  const int n1 = (M_ * E_) / 4, n2 = (3 * E_ * E_) / 4;
  const float4* src; u16* dst; int i;
  if (idx < n1)            { src = (const float4*)q;  dst = X;  i = idx; }
  else if (idx < n1 + n2)  { src = (const float4*)wi; dst = Wi; i = idx - n1; }
  else                     { src = (const float4*)wo; dst = Wo; i = idx - n1 - n2; }
  float4 v = src[i];
  uint2 o;
  o.x = (u32)f2bf(v.x) | ((u32)f2bf(v.y) << 16);
  o.y = (u32)f2bf(v.z) | ((u32)f2bf(v.w) << 16);
  *(uint2*)&dst[(size_t)i * 4] = o;
}

// ---------------- Pass B: QKV GEMM + bias + scale + RoPE -------------------
// 128x128 tile, 512 threads (8 waves as 2M x 4N, each 64x32 out) — 6 waves/
// SIMD at identical LDS/tile/FETCH footprint (the R18 TLP win).
// 2-phase dbuf + granule XOR-swizzle. Epilogue: staged-transpose.
// q is pre-scaled by HD^-0.5 * log2(e) so attention softmax can use exp2.
__global__ __launch_bounds__(512) void gemm_qkv(
    const u16* __restrict__ X, const u16* __restrict__ W,
    const float* __restrict__ bias, const float* __restrict__ rel,
    u16* __restrict__ qb, u16* __restrict__ kp, u16* __restrict__ vp) {
  const int K = E_;
  __shared__ u16 SH[16384];                         // 32KB: K-loop bufs + epilogue image
  u16 (*As)[4096] = (u16(*)[4096])SH;
  u16 (*Bs)[4096] = (u16(*)[4096])(SH + 8192);
  int orig = blockIdx.y * gridDim.x + blockIdx.x;
  int wgid = xcd_swz(orig, 32 * 24);
  const int tm = (wgid & 31) * 128, tn = (wgid >> 5) * 128;
  const int tid = threadIdx.x;
  const int w = tid >> 6, lane = tid & 63, lr = lane & 15, lg = lane >> 4;
  const int wm = (w >> 2) * 64, wn = (w & 3) * 32;
  auto stage = [&](int buf, int k0) {
    int ca = tid;                                   // granules 0..511 (1 per thread)
    int ga = ca ^ ((ca >> 3) & 3);                  // inverse-swizzled source
    gl_lds16(X + (size_t)(tm + (ga >> 2)) * K + k0 + (ga & 3) * 8,
             &As[buf][ca * 8]);
    gl_lds16(W + (size_t)(tn + (ga >> 2)) * K + k0 + (ga & 3) * 8,
             &Bs[buf][ca * 8]);
  };
  f32x4 acc[4][2] = {};
  stage(0, 0);
  __syncthreads();
  for (int it = 0; it < 32; ++it) {
    int cur = it & 1;
    if (it < 31) stage(cur ^ 1, (it + 1) * 32);
    bf16x8 af[4], bq[2];
    #pragma unroll
    for (int mi = 0; mi < 4; ++mi) {
      int ga = (wm + mi * 16 + lr) * 4 + lg; ga ^= (ga >> 3) & 3;
      af[mi] = *(const bf16x8*)&As[cur][ga * 8];
    }
    #pragma unroll
    for (int ni = 0; ni < 2; ++ni) {
      int ga = (wn + ni * 16 + lr) * 4 + lg; ga ^= (ga >> 3) & 3;
      bq[ni] = *(const bf16x8*)&Bs[cur][ga * 8];
    }
    #pragma unroll
    for (int mi = 0; mi < 4; ++mi)
      #pragma unroll
      for (int ni = 0; ni < 2; ++ni)
        acc[mi][ni] = __builtin_amdgcn_mfma_f32_16x16x32_bf16(
            af[mi], bq[ni], acc[mi][ni], 0, 0, 0);
    __syncthreads();                    // drains stage loads; cur reads done
  }
  // ---- epilogue: build LDS image (4 chunks x 4096 u16), then dump ----
  const int sect = tn >> 10;                        // uniform per block
  #pragma unroll
  for (int ni = 0; ni < 2; ++ni) {
    int n = tn + wn + ni * 16 + lr;
    float bv = bias[n];
    int nn = n & 1023;
    int d = nn & 63, i2 = d >> 1;
    int hsub = (nn >> 6) & 1;
    #pragma unroll
    for (int mi = 0; mi < 4; ++mi) {
      #pragma unroll
      for (int r = 0; r < 4; ++r) {
        int m = tm + wm + mi * 16 + lg * 4 + r;
        int t = m >> 1, bb = m & 1, tl = t & 63;
        float v = acc[mi][ni][r] + bv;
        if (sect == 0) v *= 0.18033688f;            // HD^-0.5 * log2(e)
        if (sect < 2) {                             // RoPE (uniform branch)
          float partner = __shfl_xor(v, 1);
          float sp = rel[t * HD_ + i2];
          float cp = rel[t * HD_ + 32 + i2];
          float rot = (d & 1) ? partner : -partner;
          v = v * cp + rot * sp;
        }
        int off;
        if (sect == 0)
          off = tl * 64 + d;                        // q: row-major [t][d]
        else if (sect == 1)
          off = (((tl >> 4) * 2 + (d >> 5)) << 9)   // K frag-major
              + (((d >> 3) & 3) << 7) + ((tl & 15) << 3) + (d & 7);
        else
          off = (((tl >> 5) * 4 + (d >> 4)) << 9)   // V^T frag-major
              + (((tl >> 3) & 3) << 7) + ((d & 15) << 3) + (tl & 7);
        SH[((bb << 1) | hsub) * 4096 + off] = f2bf(v);
      }
    }
  }
  __syncthreads();
  {
    // chunk c = w>>1 (= (bb<<1)|hsub); each chunk dumped by 2 waves
    int h0 = (tn & 1023) >> 6;
    int c = w >> 1, half = w & 1;
    int bb = c >> 1, hs = c & 1;
    int bh = bb * H_ + h0 + hs;
    int t0 = tm >> 1;
    u16* dst;
    if (sect == 0)      dst = qb + ((size_t)bh * T_ + t0) * HD_;
    else if (sect == 1) dst = kp + (((size_t)bh * 32 + (t0 >> 6)) << 12);
    else                dst = vp + (((size_t)bh * 32 + (t0 >> 6)) << 12);
    const u16* srcp = SH + c * 4096;
    #pragma unroll
    for (int i = 0; i < 4; ++i) {
      int g = half * 256 + i * 64 + lane;
      *(uint4*)&dst[(size_t)g * 8] = *(const uint4*)&srcp[g * 8];
    }
  }
}

// ---------------- Pass D: flash attention ----------------------------------
// 512 thr / 8 waves, 128 q rows, grid (T/128, BH) = 512 blocks = 2/CU.
// KVBLK=128: 16 iterations; LDS 64KB (2 bufs x 16KB K + 16KB V) — free,
// occupancy is grid-capped at 2/CU. K/V frag-major. Softmax log2-domain raw
// v_exp, tree reductions, lane-local defer-max, lane-partial l; P->PV
// in-register via cvt_pk + permlane swaps; T5 setprio around MFMA clusters.
__global__ __launch_bounds__(512) void attn_kernel(
    const u16* __restrict__ qbm, const u16* __restrict__ kp,
    const u16* __restrict__ vp, u16* __restrict__ attnb) {
  __shared__ u16 Kl[2][8192];                 // 2 x 16KB
  __shared__ u16 Vl[2][8192];                 // 2 x 16KB
  int orig = blockIdx.y * gridDim.x + blockIdx.x;
  int wgid = xcd_swz(orig, 16 * 32);
  int bh = wgid >> 4;
  int tid = threadIdx.x;
  int w = tid >> 6, lane = tid & 63, lr = lane & 15, lg = lane >> 4;
  int qbase = (wgid & 15) * 128 + w * 16;
  const u16* qrow  = qbm + (size_t)bh * T_ * HD_;
  const u16* ktile = kp + ((size_t)bh * 32) * 4096;
  const u16* vtile = vp + ((size_t)bh * 32) * 4096;
  bf16x8 qf[2];
  #pragma unroll
  for (int ks = 0; ks < 2; ++ks)
    qf[ks] = *(const bf16x8*)&qrow[(size_t)(qbase + lr) * HD_ + ks * 32 + lg * 8];
  auto stage = [&](int buf, int kt) {         // kt in 128-kv units
    const u16* kn = ktile + ((size_t)kt) * 8192;
    const u16* vn = vtile + ((size_t)kt) * 8192;
    gl_lds16(kn + (size_t)tid * 8,         &Kl[buf][(w * 64) * 8]);
    gl_lds16(kn + (size_t)(tid + 512) * 8, &Kl[buf][(w * 64 + 512) * 8]);
    gl_lds16(vn + (size_t)tid * 8,         &Vl[buf][(w * 64) * 8]);
    gl_lds16(vn + (size_t)(tid + 512) * 8, &Vl[buf][(w * 64 + 512) * 8]);
  };
  f32x4 o[4] = {};
  float mrun = -INFINITY, lrun = 0.f;        // lrun is LANE-PARTIAL
  stage(0, 0);
  __syncthreads();
  for (int kt = 0; kt < 16; ++kt) {
    int cur = kt & 1;
    if (kt < 15) stage(cur ^ 1, kt + 1);
    // QK^T (swapped): st[kb4][r] = S[kv = kb4*16+lg*4+r][q = lr], kb4 0..7
    f32x4 st[8];
    __builtin_amdgcn_s_setprio(1);
    #pragma unroll
    for (int kb4 = 0; kb4 < 8; ++kb4) {
      st[kb4] = (f32x4){0.f, 0.f, 0.f, 0.f};
      #pragma unroll
      for (int ks = 0; ks < 2; ++ks) {
        bf16x8 a = *(const bf16x8*)&Kl[cur][(kb4 * 2 + ks) * 512 + lane * 8];
        st[kb4] = __builtin_amdgcn_mfma_f32_16x16x32_bf16(a, qf[ks], st[kb4], 0, 0, 0);
      }
    }
    __builtin_amdgcn_s_setprio(0);
    // lane-local tree max; cross-lane shfls only when rescale triggers
    float mm[8];
    #pragma unroll
    for (int kb4 = 0; kb4 < 8; ++kb4)
      mm[kb4] = fmaxf(fmaxf(st[kb4][0], st[kb4][1]),
                      fmaxf(st[kb4][2], st[kb4][3]));
    float mxl = fmaxf(fmaxf(fmaxf(mm[0], mm[1]), fmaxf(mm[2], mm[3])),
                      fmaxf(fmaxf(mm[4], mm[5]), fmaxf(mm[6], mm[7])));
    if (!__all(mxl <= mrun + 11.5f)) {       // T13 defer-max (log2 domain)
      float mx = fmaxf(mxl, __shfl_xor(mxl, 16));
      mx = fmaxf(mx, __shfl_xor(mx, 32));
      float mnew = fmaxf(mrun, mx);
      float sc = ex2(mrun - mnew);
      lrun *= sc;                            // partial scales uniformly
      #pragma unroll
      for (int db = 0; db < 4; ++db) o[db] *= sc;
      mrun = mnew;
    }
    u32 cv[8][2];
    float s01 = 0.f, s23 = 0.f;
    #pragma unroll
    for (int kb4 = 0; kb4 < 8; ++kb4) {
      float p0 = ex2(st[kb4][0] - mrun);
      float p1 = ex2(st[kb4][1] - mrun);
      float p2 = ex2(st[kb4][2] - mrun);
      float p3 = ex2(st[kb4][3] - mrun);
      if (kb4 & 2) s23 += (p0 + p1) + (p2 + p3);
      else         s01 += (p0 + p1) + (p2 + p3);
      cv[kb4][0] = cvtpk(p0, p1);            // lo=r0, hi=r1
      cv[kb4][1] = cvtpk(p2, p3);
    }
    lrun += s01 + s23;                       // lane-partial; no shfl here
    // PV over 128 kv = 4 k-slots of 32; in-register P redistribution.
    #pragma unroll
    for (int ks = 0; ks < 4; ++ks) {
      u32 a = cv[ks * 2][0], b = cv[ks * 2][1];
      u32 c = cv[ks * 2 + 1][0], d = cv[ks * 2 + 1][1];
      asm("v_permlane32_swap_b32 %0, %1" : "+v"(a), "+v"(c));
      asm("v_permlane32_swap_b32 %0, %1" : "+v"(b), "+v"(d));
      asm("v_permlane16_swap_b32 %0, %1" : "+v"(a), "+v"(c));
      asm("v_permlane16_swap_b32 %0, %1" : "+v"(b), "+v"(d));
      u32 pf32[4] = {a, b, c, d};
      bf16x8 pf = *(const bf16x8*)pf32;
      __builtin_amdgcn_s_setprio(1);
      #pragma unroll
      for (int db = 0; db < 4; ++db) {
        bf16x8 vf = *(const bf16x8*)&Vl[cur][(ks * 4 + db) * 512 + lane * 8];
        o[db] = __builtin_amdgcn_mfma_f32_16x16x32_bf16(vf, pf, o[db], 0, 0, 0);
      }
      __builtin_amdgcn_s_setprio(0);
    }
    __syncthreads();                         // drains vmcnt: next tile ready
  }
  // final cross-lane l reduce (deferred from the loop)
  lrun += __shfl_xor(lrun, 16);
  lrun += __shfl_xor(lrun, 32);
  float inv = 1.f / lrun;
  int bb = bh >> 4, h = bh & 15;
  int m = (qbase + lr) * 2 + bb;
  #pragma unroll
  for (int db = 0; db < 4; ++db) {
    uint2 u;
    u.x = cvtpk(o[db][0] * inv, o[db][1] * inv);
    u.y = cvtpk(o[db][2] * inv, o[db][3] * inv);
    *(uint2*)&attnb[(size_t)m * E_ + h * 64 + db * 16 + lg * 4] = u;
  }
}

// ---------------- Pass E: out projection GEMM ------------------------------
// out[m][n] = sum_e A[m][e] * W[n][e] + bias[n],  fp32 out
// 64x64 tile (grid 1024 = 4 blocks/CU; LDS 16KB). 4 waves as 2M x 2N,
// each 32x32 out; 2-phase dbuf + granule swizzle.
__global__ __launch_bounds__(256) void gemm_out(
    const u16* __restrict__ A, const u16* __restrict__ W,
    const float* __restrict__ bias, float* __restrict__ out) {
  const int K = E_;
  __shared__ u16 As[2][2048];
  __shared__ u16 Bs[2][2048];
  int orig = blockIdx.y * gridDim.x + blockIdx.x;
  int wgid = xcd_swz(orig, 64 * 16);
  const int tm = (wgid & 63) * 64, tn = (wgid >> 6) * 64;
  const int tid = threadIdx.x;
  const int w = tid >> 6, lane = tid & 63, lr = lane & 15, lg = lane >> 4;
  const int wm = (w >> 1) * 32, wn = (w & 1) * 32;
  auto stage = [&](int buf, int k0) {
    int ca = w * 64 + lane;                         // granules 0..255
    int ga = ca ^ ((ca >> 3) & 3);
    gl_lds16(A + (size_t)(tm + (ga >> 2)) * K + k0 + (ga & 3) * 8,
             &As[buf][ca * 8]);
    gl_lds16(W + (size_t)(tn + (ga >> 2)) * K + k0 + (ga & 3) * 8,
             &Bs[buf][ca * 8]);
  };
  f32x4 acc[2][2] = {};
  stage(0, 0);
  __syncthreads();
  for (int it = 0; it < 32; ++it) {
    int cur = it & 1;
    if (it < 31) stage(cur ^ 1, (it + 1) * 32);
    bf16x8 af[2], bq[2];
    #pragma unroll
    for (int mi = 0; mi < 2; ++mi) {
      int ga = (wm + mi * 16 + lr) * 4 + lg; ga ^= (ga >> 3) & 3;
      af[mi] = *(const bf16x8*)&As[cur][ga * 8];
    }
    #pragma unroll
    for (int ni = 0; ni < 2; ++ni) {
      int gb = (wn + ni * 16 + lr) * 4 + lg; gb ^= (gb >> 3) & 3;
      bq[ni] = *(const bf16x8*)&Bs[cur][gb * 8];
    }
    #pragma unroll
    for (int mi = 0; mi < 2; ++mi)
      #pragma unroll
      for (int ni = 0; ni < 2; ++ni)
        acc[mi][ni] = __builtin_amdgcn_mfma_f32_16x16x32_bf16(
            af[mi], bq[ni], acc[mi][ni], 0, 0, 0);
    __syncthreads();
  }
  #pragma unroll
  for (int ni = 0; ni < 2; ++ni) {
    int n = tn + wn + ni * 16 + lr;
    float bv = bias[n];
    #pragma unroll
    for (int mi = 0; mi < 2; ++mi) {
      #pragma unroll
      for (int r = 0; r < 4; ++r) {
        int m = tm + wm + mi * 16 + lg * 4 + r;
        out[(size_t)m * E_ + n] = acc[mi][ni][r] + bv;
      }
    }
  }
}

// ---------------- launch ----------------------------------------------------
extern "C" void kernel_launch(void* const* d_in, const int* in_sizes, int n_in,
                              void* d_out, int out_size, void* d_ws, size_t ws_size,
                              hipStream_t stream) {
  const float* q   = (const float*)d_in[0];
  const float* rel = (const float*)d_in[1];
  const float* wi  = (const float*)d_in[2];
  const float* bi  = (const float*)d_in[3];
  const float* wo  = (const float*)d_in[4];
  const float* bo  = (const float*)d_in[5];
  float* out = (float*)d_out;
  char* ws = (char*)d_ws;
  // ws layout (bytes), 40 MiB total:
  u16* Xb  = (u16*)(ws);                    //  8 MiB  [4096][1024]
  u16* Wib = (u16*)(ws + 8388608);          //  6 MiB  [3072][1024]
  u16* Wob = (u16*)(ws + 14680064);         //  2 MiB  [1024][1024]
  u16* qb  = (u16*)(ws + 16777216);         //  8 MiB  [32][2048][64]
  u16* kpb = (u16*)(ws + 25165824);         //  8 MiB  [32][32][4096] frag-major
  u16* vpb = (u16*)(ws + 33554432);         //  8 MiB  [32][32][4096] frag-major
  u16* attnb = Xb;                          // overlay: X dead after gemm_qkv

  cvt_kernel<<<dim3(8192), dim3(256), 0, stream>>>(q, wi, wo, Xb, Wib, Wob);
  gemm_qkv<<<dim3(32, 24), dim3(512), 0, stream>>>(Xb, Wib, bi, rel, qb, kpb, vpb);
  attn_kernel<<<dim3(16, 32), dim3(512), 0, stream>>>(qb, kpb, vpb, attnb);
  gemm_out<<<dim3(64, 16), dim3(256), 0, stream>>>(attnb, Wob, bo, out);
}

// Round 25
// 121.176 us; speedup vs baseline: 1.1707x; 1.0072x over previous
//
#include <hip/hip_runtime.h>

// Roformer MHA: T=2048 B=2 E=1024 H=16 HD=64
#define T_  2048
#define B_  2
#define E_  1024
#define H_  16
#define HD_ 64
#define M_  4096          // T*B rows
#define N_QKV 3072        // 3*E

typedef unsigned short u16;
typedef unsigned int   u32;
typedef __attribute__((ext_vector_type(8))) __bf16 bf16x8;
typedef __attribute__((ext_vector_type(4))) float  f32x4;

__device__ inline u16 f2bf(float f) {
  u32 u = __float_as_uint(f);
  u += 0x7fffu + ((u >> 16) & 1u);   // RTNE (finite values)
  return (u16)(u >> 16);
}

__device__ inline u32 cvtpk(float lo, float hi) {   // dst.lo=bf16(lo), dst.hi=bf16(hi)
  u32 r;
  asm("v_cvt_pk_bf16_f32 %0, %1, %2" : "=v"(r) : "v"(lo), "v"(hi));
  return r;
}

// fast 2^x: raw v_exp_f32 (no OCML edge-case bloat)
__device__ inline float ex2(float x) {
#if __has_builtin(__builtin_amdgcn_exp2f)
  return __builtin_amdgcn_exp2f(x);
#else
  return __expf(x * 0.69314718f);
#endif
}

__device__ inline void gl_lds16(const u16* g, u16* l) {
  __builtin_amdgcn_global_load_lds(
      (const __attribute__((address_space(1))) u32*)g,
      (__attribute__((address_space(3))) u32*)l, 16, 0, 0);
}

// T1: bijective XCD-aware block swizzle (requires nwg % 8 == 0)
__device__ inline int xcd_swz(int orig, int nwg) {
  return (orig & 7) * (nwg >> 3) + (orig >> 3);
}

// ---------------- Pass A: fp32 -> bf16 conversion --------------------------
__global__ __launch_bounds__(256) void cvt_kernel(
    const float* __restrict__ q, const float* __restrict__ wi,
    const float* __restrict__ wo, u16* __restrict__ X,
    u16* __restrict__ Wi, u16* __restrict__ Wo) {
  int idx = blockIdx.x * 256 + threadIdx.x;       // one float4 per thread
  const int n1 = (M_ * E_) / 4, n2 = (3 * E_ * E_) / 4;
  const float4* src; u16* dst; int i;
  if (idx < n1)            { src = (const float4*)q;  dst = X;  i = idx; }
  else if (idx < n1 + n2)  { src = (const float4*)wi; dst = Wi; i = idx - n1; }
  else                     { src = (const float4*)wo; dst = Wo; i = idx - n1 - n2; }
  float4 v = src[i];
  uint2 o;
  o.x = (u32)f2bf(v.x) | ((u32)f2bf(v.y) << 16);
  o.y = (u32)f2bf(v.z) | ((u32)f2bf(v.w) << 16);
  *(uint2*)&dst[(size_t)i * 4] = o;
}

// ---------------- Pass B: QKV GEMM + bias + scale + RoPE -------------------
// 128x128 tile, 512 threads (8 waves as 2M x 4N, each 64x32 out) — 6 waves/
// SIMD at identical LDS/tile/FETCH footprint (the R18 TLP win).
// 2-phase dbuf + granule XOR-swizzle. Epilogue: staged-transpose.
// q is pre-scaled by HD^-0.5 * log2(e) so attention softmax can use exp2.
__global__ __launch_bounds__(512) void gemm_qkv(
    const u16* __restrict__ X, const u16* __restrict__ W,
    const float* __restrict__ bias, const float* __restrict__ rel,
    u16* __restrict__ qb, u16* __restrict__ kp, u16* __restrict__ vp) {
  const int K = E_;
  __shared__ u16 SH[16384];                         // 32KB: K-loop bufs + epilogue image
  u16 (*As)[4096] = (u16(*)[4096])SH;
  u16 (*Bs)[4096] = (u16(*)[4096])(SH + 8192);
  int orig = blockIdx.y * gridDim.x + blockIdx.x;
  int wgid = xcd_swz(orig, 32 * 24);
  const int tm = (wgid & 31) * 128, tn = (wgid >> 5) * 128;
  const int tid = threadIdx.x;
  const int w = tid >> 6, lane = tid & 63, lr = lane & 15, lg = lane >> 4;
  const int wm = (w >> 2) * 64, wn = (w & 3) * 32;
  auto stage = [&](int buf, int k0) {
    int ca = tid;                                   // granules 0..511 (1 per thread)
    int ga = ca ^ ((ca >> 3) & 3);                  // inverse-swizzled source
    gl_lds16(X + (size_t)(tm + (ga >> 2)) * K + k0 + (ga & 3) * 8,
             &As[buf][ca * 8]);
    gl_lds16(W + (size_t)(tn + (ga >> 2)) * K + k0 + (ga & 3) * 8,
             &Bs[buf][ca * 8]);
  };
  f32x4 acc[4][2] = {};
  stage(0, 0);
  __syncthreads();
  for (int it = 0; it < 32; ++it) {
    int cur = it & 1;
    if (it < 31) stage(cur ^ 1, (it + 1) * 32);
    bf16x8 af[4], bq[2];
    #pragma unroll
    for (int mi = 0; mi < 4; ++mi) {
      int ga = (wm + mi * 16 + lr) * 4 + lg; ga ^= (ga >> 3) & 3;
      af[mi] = *(const bf16x8*)&As[cur][ga * 8];
    }
    #pragma unroll
    for (int ni = 0; ni < 2; ++ni) {
      int ga = (wn + ni * 16 + lr) * 4 + lg; ga ^= (ga >> 3) & 3;
      bq[ni] = *(const bf16x8*)&Bs[cur][ga * 8];
    }
    #pragma unroll
    for (int mi = 0; mi < 4; ++mi)
      #pragma unroll
      for (int ni = 0; ni < 2; ++ni)
        acc[mi][ni] = __builtin_amdgcn_mfma_f32_16x16x32_bf16(
            af[mi], bq[ni], acc[mi][ni], 0, 0, 0);
    __syncthreads();                    // drains stage loads; cur reads done
  }
  // ---- epilogue: build LDS image (4 chunks x 4096 u16), then dump ----
  const int sect = tn >> 10;                        // uniform per block
  #pragma unroll
  for (int ni = 0; ni < 2; ++ni) {
    int n = tn + wn + ni * 16 + lr;
    float bv = bias[n];
    int nn = n & 1023;
    int d = nn & 63, i2 = d >> 1;
    int hsub = (nn >> 6) & 1;
    #pragma unroll
    for (int mi = 0; mi < 4; ++mi) {
      #pragma unroll
      for (int r = 0; r < 4; ++r) {
        int m = tm + wm + mi * 16 + lg * 4 + r;
        int t = m >> 1, bb = m & 1, tl = t & 63;
        float v = acc[mi][ni][r] + bv;
        if (sect == 0) v *= 0.18033688f;            // HD^-0.5 * log2(e)
        if (sect < 2) {                             // RoPE (uniform branch)
          float partner = __shfl_xor(v, 1);
          float sp = rel[t * HD_ + i2];
          float cp = rel[t * HD_ + 32 + i2];
          float rot = (d & 1) ? partner : -partner;
          v = v * cp + rot * sp;
        }
        int off;
        if (sect == 0)
          off = tl * 64 + d;                        // q: row-major [t][d]
        else if (sect == 1)
          off = (((tl >> 4) * 2 + (d >> 5)) << 9)   // K frag-major
              + (((d >> 3) & 3) << 7) + ((tl & 15) << 3) + (d & 7);
        else
          off = (((tl >> 5) * 4 + (d >> 4)) << 9)   // V^T frag-major
              + (((tl >> 3) & 3) << 7) + ((d & 15) << 3) + (tl & 7);
        SH[((bb << 1) | hsub) * 4096 + off] = f2bf(v);
      }
    }
  }
  __syncthreads();
  {
    // chunk c = w>>1 (= (bb<<1)|hsub); each chunk dumped by 2 waves
    int h0 = (tn & 1023) >> 6;
    int c = w >> 1, half = w & 1;
    int bb = c >> 1, hs = c & 1;
    int bh = bb * H_ + h0 + hs;
    int t0 = tm >> 1;
    u16* dst;
    if (sect == 0)      dst = qb + ((size_t)bh * T_ + t0) * HD_;
    else if (sect == 1) dst = kp + (((size_t)bh * 32 + (t0 >> 6)) << 12);
    else                dst = vp + (((size_t)bh * 32 + (t0 >> 6)) << 12);
    const u16* srcp = SH + c * 4096;
    #pragma unroll
    for (int i = 0; i < 4; ++i) {
      int g = half * 256 + i * 64 + lane;
      *(uint4*)&dst[(size_t)g * 8] = *(const uint4*)&srcp[g * 8];
    }
  }
}

// ---------------- Pass D: flash attention ----------------------------------
// 512 thr / 8 waves, 128 q rows, grid (T/128, BH) = 512 blocks = 2/CU.
// KVBLK=128 (16 iters), LDS 64KB, K/V frag-major 2-phase dbuf.
// SM-SPLIT (m214 r283 analog): softmax+PV interleaved PER K-SLOT — four
// alternating VALU(8 exp + cvt/permlane) / MFMA(4 PV) segments per iter so
// co-resident waves' phases dovetail, instead of one big VALU block then
// one big MFMA block. Math per slot unchanged. T5 setprio on MFMA clusters.
__global__ __launch_bounds__(512) void attn_kernel(
    const u16* __restrict__ qbm, const u16* __restrict__ kp,
    const u16* __restrict__ vp, u16* __restrict__ attnb) {
  __shared__ u16 Kl[2][8192];                 // 2 x 16KB
  __shared__ u16 Vl[2][8192];                 // 2 x 16KB
  int orig = blockIdx.y * gridDim.x + blockIdx.x;
  int wgid = xcd_swz(orig, 16 * 32);
  int bh = wgid >> 4;
  int tid = threadIdx.x;
  int w = tid >> 6, lane = tid & 63, lr = lane & 15, lg = lane >> 4;
  int qbase = (wgid & 15) * 128 + w * 16;
  const u16* qrow  = qbm + (size_t)bh * T_ * HD_;
  const u16* ktile = kp + ((size_t)bh * 32) * 4096;
  const u16* vtile = vp + ((size_t)bh * 32) * 4096;
  bf16x8 qf[2];
  #pragma unroll
  for (int ks = 0; ks < 2; ++ks)
    qf[ks] = *(const bf16x8*)&qrow[(size_t)(qbase + lr) * HD_ + ks * 32 + lg * 8];
  auto stage = [&](int buf, int kt) {         // kt in 128-kv units
    const u16* kn = ktile + ((size_t)kt) * 8192;
    const u16* vn = vtile + ((size_t)kt) * 8192;
    gl_lds16(kn + (size_t)tid * 8,         &Kl[buf][(w * 64) * 8]);
    gl_lds16(kn + (size_t)(tid + 512) * 8, &Kl[buf][(w * 64 + 512) * 8]);
    gl_lds16(vn + (size_t)tid * 8,         &Vl[buf][(w * 64) * 8]);
    gl_lds16(vn + (size_t)(tid + 512) * 8, &Vl[buf][(w * 64 + 512) * 8]);
  };
  f32x4 o[4] = {};
  float mrun = -INFINITY, lrun = 0.f;        // lrun is LANE-PARTIAL
  stage(0, 0);
  __syncthreads();
  for (int kt = 0; kt < 16; ++kt) {
    int cur = kt & 1;
    if (kt < 15) stage(cur ^ 1, kt + 1);
    // QK^T (swapped): st[kb4][r] = S[kv = kb4*16+lg*4+r][q = lr], kb4 0..7
    f32x4 st[8];
    __builtin_amdgcn_s_setprio(1);
    #pragma unroll
    for (int kb4 = 0; kb4 < 8; ++kb4) {
      st[kb4] = (f32x4){0.f, 0.f, 0.f, 0.f};
      #pragma unroll
      for (int ks = 0; ks < 2; ++ks) {
        bf16x8 a = *(const bf16x8*)&Kl[cur][(kb4 * 2 + ks) * 512 + lane * 8];
        st[kb4] = __builtin_amdgcn_mfma_f32_16x16x32_bf16(a, qf[ks], st[kb4], 0, 0, 0);
      }
    }
    __builtin_amdgcn_s_setprio(0);
    // lane-local tree max; cross-lane shfls only when rescale triggers
    float mm[8];
    #pragma unroll
    for (int kb4 = 0; kb4 < 8; ++kb4)
      mm[kb4] = fmaxf(fmaxf(st[kb4][0], st[kb4][1]),
                      fmaxf(st[kb4][2], st[kb4][3]));
    float mxl = fmaxf(fmaxf(fmaxf(mm[0], mm[1]), fmaxf(mm[2], mm[3])),
                      fmaxf(fmaxf(mm[4], mm[5]), fmaxf(mm[6], mm[7])));
    if (!__all(mxl <= mrun + 11.5f)) {       // T13 defer-max (log2 domain)
      float mx = fmaxf(mxl, __shfl_xor(mxl, 16));
      mx = fmaxf(mx, __shfl_xor(mx, 32));
      float mnew = fmaxf(mrun, mx);
      float sc = ex2(mrun - mnew);
      lrun *= sc;                            // partial scales uniformly
      #pragma unroll
      for (int db = 0; db < 4; ++db) o[db] *= sc;
      mrun = mnew;
    }
    // SM-SPLIT: per k-slot, exp(8)+pack -> permlane -> 4 PV MFMA
    float s01 = 0.f, s23 = 0.f;
    #pragma unroll
    for (int ks = 0; ks < 4; ++ks) {
      float p0 = ex2(st[ks * 2][0] - mrun);
      float p1 = ex2(st[ks * 2][1] - mrun);
      float p2 = ex2(st[ks * 2][2] - mrun);
      float p3 = ex2(st[ks * 2][3] - mrun);
      float p4 = ex2(st[ks * 2 + 1][0] - mrun);
      float p5 = ex2(st[ks * 2 + 1][1] - mrun);
      float p6 = ex2(st[ks * 2 + 1][2] - mrun);
      float p7 = ex2(st[ks * 2 + 1][3] - mrun);
      s01 += (p0 + p1) + (p2 + p3);
      s23 += (p4 + p5) + (p6 + p7);
      u32 a = cvtpk(p0, p1), b = cvtpk(p2, p3);
      u32 c = cvtpk(p4, p5), d = cvtpk(p6, p7);
      asm("v_permlane32_swap_b32 %0, %1" : "+v"(a), "+v"(c));
      asm("v_permlane32_swap_b32 %0, %1" : "+v"(b), "+v"(d));
      asm("v_permlane16_swap_b32 %0, %1" : "+v"(a), "+v"(c));
      asm("v_permlane16_swap_b32 %0, %1" : "+v"(b), "+v"(d));
      u32 pf32[4] = {a, b, c, d};
      bf16x8 pf = *(const bf16x8*)pf32;
      __builtin_amdgcn_s_setprio(1);
      #pragma unroll
      for (int db = 0; db < 4; ++db) {
        bf16x8 vf = *(const bf16x8*)&Vl[cur][(ks * 4 + db) * 512 + lane * 8];
        o[db] = __builtin_amdgcn_mfma_f32_16x16x32_bf16(vf, pf, o[db], 0, 0, 0);
      }
      __builtin_amdgcn_s_setprio(0);
    }
    lrun += s01 + s23;                       // lane-partial; no shfl here
    __syncthreads();                         // drains vmcnt: next tile ready
  }
  // final cross-lane l reduce (deferred from the loop)
  lrun += __shfl_xor(lrun, 16);
  lrun += __shfl_xor(lrun, 32);
  float inv = 1.f / lrun;
  int bb = bh >> 4, h = bh & 15;
  int m = (qbase + lr) * 2 + bb;
  #pragma unroll
  for (int db = 0; db < 4; ++db) {
    uint2 u;
    u.x = cvtpk(o[db][0] * inv, o[db][1] * inv);
    u.y = cvtpk(o[db][2] * inv, o[db][3] * inv);
    *(uint2*)&attnb[(size_t)m * E_ + h * 64 + db * 16 + lg * 4] = u;
  }
}

// ---------------- Pass E: out projection GEMM ------------------------------
// out[m][n] = sum_e A[m][e] * W[n][e] + bias[n],  fp32 out
// 64x64 tile (grid 1024 = 4 blocks/CU; LDS 16KB). 4 waves as 2M x 2N,
// each 32x32 out; 2-phase dbuf + granule swizzle.
__global__ __launch_bounds__(256) void gemm_out(
    const u16* __restrict__ A, const u16* __restrict__ W,
    const float* __restrict__ bias, float* __restrict__ out) {
  const int K = E_;
  __shared__ u16 As[2][2048];
  __shared__ u16 Bs[2][2048];
  int orig = blockIdx.y * gridDim.x + blockIdx.x;
  int wgid = xcd_swz(orig, 64 * 16);
  const int tm = (wgid & 63) * 64, tn = (wgid >> 6) * 64;
  const int tid = threadIdx.x;
  const int w = tid >> 6, lane = tid & 63, lr = lane & 15, lg = lane >> 4;
  const int wm = (w >> 1) * 32, wn = (w & 1) * 32;
  auto stage = [&](int buf, int k0) {
    int ca = w * 64 + lane;                         // granules 0..255
    int ga = ca ^ ((ca >> 3) & 3);
    gl_lds16(A + (size_t)(tm + (ga >> 2)) * K + k0 + (ga & 3) * 8,
             &As[buf][ca * 8]);
    gl_lds16(W + (size_t)(tn + (ga >> 2)) * K + k0 + (ga & 3) * 8,
             &Bs[buf][ca * 8]);
  };
  f32x4 acc[2][2] = {};
  stage(0, 0);
  __syncthreads();
  for (int it = 0; it < 32; ++it) {
    int cur = it & 1;
    if (it < 31) stage(cur ^ 1, (it + 1) * 32);
    bf16x8 af[2], bq[2];
    #pragma unroll
    for (int mi = 0; mi < 2; ++mi) {
      int ga = (wm + mi * 16 + lr) * 4 + lg; ga ^= (ga >> 3) & 3;
      af[mi] = *(const bf16x8*)&As[cur][ga * 8];
    }
    #pragma unroll
    for (int ni = 0; ni < 2; ++ni) {
      int gb = (wn + ni * 16 + lr) * 4 + lg; gb ^= (gb >> 3) & 3;
      bq[ni] = *(const bf16x8*)&Bs[cur][gb * 8];
    }
    #pragma unroll
    for (int mi = 0; mi < 2; ++mi)
      #pragma unroll
      for (int ni = 0; ni < 2; ++ni)
        acc[mi][ni] = __builtin_amdgcn_mfma_f32_16x16x32_bf16(
            af[mi], bq[ni], acc[mi][ni], 0, 0, 0);
    __syncthreads();
  }
  #pragma unroll
  for (int ni = 0; ni < 2; ++ni) {
    int n = tn + wn + ni * 16 + lr;
    float bv = bias[n];
    #pragma unroll
    for (int mi = 0; mi < 2; ++mi) {
      #pragma unroll
      for (int r = 0; r < 4; ++r) {
        int m = tm + wm + mi * 16 + lg * 4 + r;
        out[(size_t)m * E_ + n] = acc[mi][ni][r] + bv;
      }
    }
  }
}

// ---------------- launch ----------------------------------------------------
extern "C" void kernel_launch(void* const* d_in, const int* in_sizes, int n_in,
                              void* d_out, int out_size, void* d_ws, size_t ws_size,
                              hipStream_t stream) {
  const float* q   = (const float*)d_in[0];
  const float* rel = (const float*)d_in[1];
  const float* wi  = (const float*)d_in[2];
  const float* bi  = (const float*)d_in[3];
  const float* wo  = (const float*)d_in[4];
  const float* bo  = (const float*)d_in[5];
  float* out = (float*)d_out;
  char* ws = (char*)d_ws;
  // ws layout (bytes), 40 MiB total:
  u16* Xb  = (u16*)(ws);                    //  8 MiB  [4096][1024]
  u16* Wib = (u16*)(ws + 8388608);          //  6 MiB  [3072][1024]
  u16* Wob = (u16*)(ws + 14680064);         //  2 MiB  [1024][1024]
  u16* qb  = (u16*)(ws + 16777216);         //  8 MiB  [32][2048][64]
  u16* kpb = (u16*)(ws + 25165824);         //  8 MiB  [32][32][4096] frag-major
  u16* vpb = (u16*)(ws + 33554432);         //  8 MiB  [32][32][4096] frag-major
  u16* attnb = Xb;                          // overlay: X dead after gemm_qkv

  cvt_kernel<<<dim3(8192), dim3(256), 0, stream>>>(q, wi, wo, Xb, Wib, Wob);
  gemm_qkv<<<dim3(32, 24), dim3(512), 0, stream>>>(Xb, Wib, bi, rel, qb, kpb, vpb);
  attn_kernel<<<dim3(16, 32), dim3(512), 0, stream>>>(qb, kpb, vpb, attnb);
  gemm_out<<<dim3(64, 16), dim3(256), 0, stream>>>(attnb, Wob, bo, out);
}